// Round 1
// baseline (82.321 us; speedup 1.0000x reference)
//
#include <hip/hip_runtime.h>

// BioSelfAttention: B=4 H=8 T=128 D=64
// Phase 1: J_qk = rowdot(Q,K) -> LIF -> WTA(n=128 per bh row)
// Phase 2: J_v = rates * V -> LIF per element
// Phase 3: WTA(n=8192 per bh row) -> out
//
// WTA closed form: W = -0.9 + 2.0*I on diag(1.1); x@W^T [j] = 2*x_j - 0.9*S
// => x_j <- clip(3*x_j - 0.9*S, 0, 1),  S = sum(x)

#define NBH 32      // B*H
#define TT  128
#define DD  64
#define ROW2 8192   // T*D

__device__ __forceinline__ float lif_rate(float J) {
    // v_{n+1} = v + 0.05*(J - v) <= max(J,0) (+~2ulp); threshold 1.0.
    // If J < 0.999 the neuron can never spike -> rate exactly 0.
    if (J < 0.999f) return 0.0f;
    float v = 0.0f;
    float cnt = 0.0f;
#pragma unroll
    for (int s = 0; s < 100; ++s) {
        v += 0.05f * (J - v);
        if (v >= 1.0f) { cnt += 1.0f; v = 0.0f; }
    }
    return cnt / 100.0f;
}

// K1: 32 blocks x 128 threads. Thread t: dot(Q[bh,t,:],K[bh,t,:]), LIF,
// then 20-iter WTA across the 128 threads of the block.
__global__ void k_rates(const float* __restrict__ Q,
                        const float* __restrict__ K,
                        float* __restrict__ rates) {
    const int bh = blockIdx.x;
    const int t  = threadIdx.x;          // 0..127
    const float4* q4 = (const float4*)(Q + ((size_t)bh * TT + t) * DD);
    const float4* k4 = (const float4*)(K + ((size_t)bh * TT + t) * DD);
    float J = 0.0f;
#pragma unroll
    for (int i = 0; i < DD / 4; ++i) {
        float4 a = q4[i], b = k4[i];
        J += a.x * b.x + a.y * b.y + a.z * b.z + a.w * b.w;
    }

    float x = lif_rate(J);

    __shared__ float partial[2];
    for (int it = 0; it < 20; ++it) {
        float s = x;
#pragma unroll
        for (int off = 1; off < 64; off <<= 1) s += __shfl_xor(s, off);
        if ((t & 63) == 0) partial[t >> 6] = s;
        __syncthreads();
        float S = partial[0] + partial[1];
        x = 3.0f * x - 0.9f * S;
        x = fminf(fmaxf(x, 0.0f), 1.0f);
        __syncthreads();
    }
    rates[bh * TT + t] = x;
}

// K2: elementwise LIF on J_v = rates * V. 262144 threads.
__global__ void k_lif_v(const float* __restrict__ V,
                        const float* __restrict__ rates,
                        float* __restrict__ ctx) {
    const int idx = blockIdx.x * blockDim.x + threadIdx.x;  // < 262144
    const float r = rates[idx >> 6];     // idx>>6 == bh*128 + t
    const float J = r * V[idx];
    ctx[idx] = lif_rate(J);
}

// K3: WTA over 8192 units per bh row, in-place on out. 32 blocks x 1024 thr,
// 8 elements/thread held in registers.
__global__ void k_wta2(float* __restrict__ out) {
    const int bh  = blockIdx.x;
    const int tid = threadIdx.x;         // 0..1023
    float* x = out + (size_t)bh * ROW2;

    float vals[8];
#pragma unroll
    for (int i = 0; i < 8; ++i) vals[i] = x[tid + i * 1024];

    __shared__ float partial[16];
    for (int it = 0; it < 20; ++it) {
        float s = vals[0] + vals[1] + vals[2] + vals[3]
                + vals[4] + vals[5] + vals[6] + vals[7];
#pragma unroll
        for (int off = 1; off < 64; off <<= 1) s += __shfl_xor(s, off);
        if ((tid & 63) == 0) partial[tid >> 6] = s;
        __syncthreads();
        float S = 0.0f;
#pragma unroll
        for (int i = 0; i < 16; ++i) S += partial[i];
        const float c = 0.9f * S;
#pragma unroll
        for (int i = 0; i < 8; ++i) {
            float v = 3.0f * vals[i] - c;
            vals[i] = fminf(fmaxf(v, 0.0f), 1.0f);
        }
        __syncthreads();
    }
#pragma unroll
    for (int i = 0; i < 8; ++i) x[tid + i * 1024] = vals[i];
}

extern "C" void kernel_launch(void* const* d_in, const int* in_sizes, int n_in,
                              void* d_out, int out_size, void* d_ws, size_t ws_size,
                              hipStream_t stream) {
    const float* Q = (const float*)d_in[0];
    const float* K = (const float*)d_in[1];
    const float* V = (const float*)d_in[2];
    float* out   = (float*)d_out;
    float* rates = (float*)d_ws;   // 4096 floats = 16 KB

    k_rates<<<NBH, TT, 0, stream>>>(Q, K, rates);
    k_lif_v<<<512, 512, 0, stream>>>(V, rates, out);
    k_wta2<<<NBH, 1024, 0, stream>>>(out);
}

// Round 2
// 80.520 us; speedup vs baseline: 1.0224x; 1.0224x over previous
//
#include <hip/hip_runtime.h>

// BioSelfAttention: B=4 H=8 T=128 D=64 — fully fused, one block per (b,h).
// Phase A: J_qk[t] = dot(Q[bh,t,:], K[bh,t,:])   (threads 0..127, order
//          identical to round-1 kernel: sequential float4 chunks)
// Phase B: rates[t] = LIF(J_qk[t])
// Phase C: WTA-128 (20 iters, block-local)
// Phase D: ctx[e] = LIF(rates[e>>6] * V[bh,e])   (8 elems/thread in regs)
// Phase E: WTA-8192 (20 iters, block-local, registers)
//
// WTA closed form: x_j <- clip(3*x_j - 0.9*S, 0, 1), S = sum(x).

#define NBH  32
#define TT   128
#define DD   64
#define ROW2 8192

__device__ __forceinline__ float lif_rate(float J) {
    // v' = v + 0.05*(J - v); v stays < J+eps, so J < 0.999 => never spikes.
    if (J < 0.999f) return 0.0f;
    float v = 0.0f;
    float cnt = 0.0f;
#pragma unroll
    for (int s = 0; s < 100; ++s) {
        v += 0.05f * (J - v);
        if (v >= 1.0f) { cnt += 1.0f; v = 0.0f; }
    }
    return cnt / 100.0f;
}

__global__ void __launch_bounds__(1024)
k_fused(const float* __restrict__ Q, const float* __restrict__ K,
        const float* __restrict__ V, float* __restrict__ out) {
    const int bh  = blockIdx.x;
    const int tid = threadIdx.x;            // 0..1023

    __shared__ float xrow[TT];
    __shared__ float partial[16];

    // ---- Phase A+B: per-row dot + LIF (threads 0..127, one row each) ----
    float x = 0.0f;
    if (tid < TT) {
        const float4* q4 = (const float4*)(Q + ((size_t)bh * TT + tid) * DD);
        const float4* k4 = (const float4*)(K + ((size_t)bh * TT + tid) * DD);
        float J = 0.0f;
#pragma unroll
        for (int i = 0; i < DD / 4; ++i) {
            float4 a = q4[i], b = k4[i];
            J += a.x * b.x + a.y * b.y + a.z * b.z + a.w * b.w;
        }
        x = lif_rate(J);
    }

    // ---- Phase C: WTA over the 128 rates (waves 0,1 active) ----
    for (int it = 0; it < 20; ++it) {
        if (tid < TT) {
            float s = x;
#pragma unroll
            for (int off = 1; off < 64; off <<= 1) s += __shfl_xor(s, off);
            if ((tid & 63) == 0) partial[tid >> 6] = s;
        }
        __syncthreads();
        if (tid < TT) {
            float S = partial[0] + partial[1];
            x = 3.0f * x - 0.9f * S;
            x = fminf(fmaxf(x, 0.0f), 1.0f);
        }
        __syncthreads();
    }
    if (tid < TT) xrow[tid] = x;
    __syncthreads();

    // ---- Phase D: elementwise LIF on rates * V (8 elems/thread) ----
    const float* Vrow = V + (size_t)bh * ROW2;
    float vals[8];
#pragma unroll
    for (int i = 0; i < 8; ++i) {
        const int e = tid + i * 1024;
        vals[i] = lif_rate(xrow[e >> 6] * Vrow[e]);
    }
    __syncthreads();

    // ---- Phase E: WTA over 8192 units (registers, 16 waves) ----
    for (int it = 0; it < 20; ++it) {
        float s = vals[0] + vals[1] + vals[2] + vals[3]
                + vals[4] + vals[5] + vals[6] + vals[7];
#pragma unroll
        for (int off = 1; off < 64; off <<= 1) s += __shfl_xor(s, off);
        if ((tid & 63) == 0) partial[tid >> 6] = s;
        __syncthreads();
        float S = 0.0f;
#pragma unroll
        for (int i = 0; i < 16; ++i) S += partial[i];
        const float c = 0.9f * S;
#pragma unroll
        for (int i = 0; i < 8; ++i) {
            float v = 3.0f * vals[i] - c;
            vals[i] = fminf(fmaxf(v, 0.0f), 1.0f);
        }
        __syncthreads();
    }

    float* orow = out + (size_t)bh * ROW2;
#pragma unroll
    for (int i = 0; i < 8; ++i) orow[tid + i * 1024] = vals[i];
}

extern "C" void kernel_launch(void* const* d_in, const int* in_sizes, int n_in,
                              void* d_out, int out_size, void* d_ws, size_t ws_size,
                              hipStream_t stream) {
    const float* Q = (const float*)d_in[0];
    const float* K = (const float*)d_in[1];
    const float* V = (const float*)d_in[2];
    float* out = (float*)d_out;
    k_fused<<<NBH, 1024, 0, stream>>>(Q, K, V, out);
}

// Round 6
// 64.243 us; speedup vs baseline: 1.2814x; 1.2534x over previous
//
#include <hip/hip_runtime.h>

// BioSelfAttention: B=4 H=8 T=128 D=64 — fully fused, one block per (b,h).
//   A: J_qk[t] = dot(Q[bh,t,:], K[bh,t,:])   (threads 0..127, sequential
//      float4 chunks — bit-identical to the verified round-1 order)
//   B: rates[t] = LIF(J_qk[t])
//   C: WTA-128, single-wave (lane holds t and t+64), shfl-only, early exit
//   D: ctx[e] = LIF(rates[e>>6] * V[bh,e])   (8 elems/thread in regs)
//   E: WTA-8192 block-wide, early exit
//
// WTA closed form: x_j <- clip(3*x_j - 0.9*S, 0, 1), S = sum(x).
// Early exit: x>=0 always, so S==0  <=>  all x==0, an exact fixed point
// (clip(3*0 - 0) = 0). Breaking then is bit-exact vs running all 20 iters.

#define NBH  32
#define TT   128
#define DD   64
#define ROW2 8192

__device__ __forceinline__ float lif_rate(float J) {
    // v' = v + 0.05*(J - v); v stays <= max(J,0)+eps, so J<0.999 => rate 0.
    if (J < 0.999f) return 0.0f;
    float v = 0.0f;
    float cnt = 0.0f;
#pragma unroll
    for (int s = 0; s < 100; ++s) {
        v += 0.05f * (J - v);
        if (v >= 1.0f) { cnt += 1.0f; v = 0.0f; }
    }
    return cnt / 100.0f;
}

__device__ __forceinline__ float clip01(float v) {
    return fminf(fmaxf(v, 0.0f), 1.0f);
}

__global__ void __launch_bounds__(1024)
k_fused(const float* __restrict__ Q, const float* __restrict__ K,
        const float* __restrict__ V, float* __restrict__ out) {
    const int bh  = blockIdx.x;
    const int tid = threadIdx.x;            // 0..1023

    __shared__ float xrow[TT];
    __shared__ float partial[16];

    // ---- Phase A+B: per-row dot + LIF (threads 0..127, one row each) ----
    if (tid < TT) {
        const float4* q4 = (const float4*)(Q + ((size_t)bh * TT + tid) * DD);
        const float4* k4 = (const float4*)(K + ((size_t)bh * TT + tid) * DD);
        float J = 0.0f;
#pragma unroll
        for (int i = 0; i < DD / 4; ++i) {
            float4 a = q4[i], b = k4[i];
            J += a.x * b.x + a.y * b.y + a.z * b.z + a.w * b.w;
        }
        xrow[tid] = lif_rate(J);
    }
    __syncthreads();

    // ---- Phase C: WTA-128 in wave 0 only (no barriers in loop) ----
    if (tid < 64) {
        float x0 = xrow[tid];
        float x1 = xrow[tid + 64];
        for (int it = 0; it < 20; ++it) {
            float s = x0 + x1;
#pragma unroll
            for (int off = 1; off < 64; off <<= 1) s += __shfl_xor(s, off);
            if (s == 0.0f) break;            // exact fixed point
            x0 = clip01(3.0f * x0 - 0.9f * s);
            x1 = clip01(3.0f * x1 - 0.9f * s);
        }
        xrow[tid]      = x0;
        xrow[tid + 64] = x1;
    }
    __syncthreads();

    // ---- Phase D: elementwise LIF on rates * V (8 elems/thread) ----
    const float* Vrow = V + (size_t)bh * ROW2;
    float vals[8];
#pragma unroll
    for (int i = 0; i < 8; ++i) {
        const int e = tid + i * 1024;
        vals[i] = lif_rate(xrow[e >> 6] * Vrow[e]);
    }
    __syncthreads();

    // ---- Phase E: WTA-8192 block-wide (registers, 16 waves) ----
    for (int it = 0; it < 20; ++it) {
        float s = vals[0] + vals[1] + vals[2] + vals[3]
                + vals[4] + vals[5] + vals[6] + vals[7];
#pragma unroll
        for (int off = 1; off < 64; off <<= 1) s += __shfl_xor(s, off);
        if ((tid & 63) == 0) partial[tid >> 6] = s;
        __syncthreads();
        float S = 0.0f;
#pragma unroll
        for (int i = 0; i < 16; ++i) S += partial[i];
        if (S == 0.0f) break;                // uniform across block: exact FP
        const float c = 0.9f * S;
#pragma unroll
        for (int i = 0; i < 8; ++i)
            vals[i] = clip01(3.0f * vals[i] - c);
        __syncthreads();
    }

    float* orow = out + (size_t)bh * ROW2;
#pragma unroll
    for (int i = 0; i < 8; ++i) orow[tid + i * 1024] = vals[i];
}

extern "C" void kernel_launch(void* const* d_in, const int* in_sizes, int n_in,
                              void* d_out, int out_size, void* d_ws, size_t ws_size,
                              hipStream_t stream) {
    const float* Q = (const float*)d_in[0];
    const float* K = (const float*)d_in[1];
    const float* V = (const float*)d_in[2];
    float* out = (float*)d_out;
    k_fused<<<NBH, 1024, 0, stream>>>(Q, K, V, out);
}

// Round 12
// 62.521 us; speedup vs baseline: 1.3167x; 1.0276x over previous
//
#include <hip/hip_runtime.h>

// BioSelfAttention: B=4 H=8 T=128 D=64 — fully fused, one block per (b,h).
//   A: J_qk[t] = dot(Q[bh,t,:], K[bh,t,:])   (threads 0..127, sequential
//      float4 chunks — bit-identical to the verified round-1 order)
//   B: rates[t] = LIF(J_qk[t])
//   C: WTA-128, single-wave (lane holds t and t+64), shfl-only, early exit
//   D: ctx[e] = LIF(rates[e>>6] * V[bh,e])   (8 elems/thread in regs;
//      V load + LIF skipped when the group's rate is 0 — wave-uniform branch,
//      exact for finite V since 0*V = 0 and lif_rate(0) = 0)
//   E: WTA-8192 block-wide, early exit
//
// WTA closed form: x_j <- clip(3*x_j - 0.9*S, 0, 1), S = sum(x).
// Early exit: x>=0 always, so S==0  <=>  all x==0, an exact fixed point
// (clip(3*0 - 0) = 0). Breaking then is bit-exact vs running all 20 iters.

#define NBH  32
#define TT   128
#define DD   64
#define ROW2 8192

__device__ __forceinline__ float lif_rate(float J) {
    // v' = v + 0.05*(J - v); v stays <= max(J,0)+eps, so J<0.999 => rate 0.
    if (J < 0.999f) return 0.0f;
    float v = 0.0f;
    float cnt = 0.0f;
#pragma unroll
    for (int s = 0; s < 100; ++s) {
        v += 0.05f * (J - v);
        if (v >= 1.0f) { cnt += 1.0f; v = 0.0f; }
    }
    return cnt / 100.0f;
}

__device__ __forceinline__ float clip01(float v) {
    return fminf(fmaxf(v, 0.0f), 1.0f);
}

__global__ void __launch_bounds__(1024)
k_fused(const float* __restrict__ Q, const float* __restrict__ K,
        const float* __restrict__ V, float* __restrict__ out) {
    const int bh  = blockIdx.x;
    const int tid = threadIdx.x;            // 0..1023

    __shared__ float xrow[TT];
    __shared__ float partial[16];

    // ---- Phase A+B: per-row dot + LIF (threads 0..127, one row each) ----
    if (tid < TT) {
        const float4* q4 = (const float4*)(Q + ((size_t)bh * TT + tid) * DD);
        const float4* k4 = (const float4*)(K + ((size_t)bh * TT + tid) * DD);
        float J = 0.0f;
#pragma unroll
        for (int i = 0; i < DD / 4; ++i) {
            float4 a = q4[i], b = k4[i];
            J += a.x * b.x + a.y * b.y + a.z * b.z + a.w * b.w;
        }
        xrow[tid] = lif_rate(J);
    }
    __syncthreads();

    // ---- Phase C: WTA-128 in wave 0 only (no barriers in loop) ----
    if (tid < 64) {
        float x0 = xrow[tid];
        float x1 = xrow[tid + 64];
        for (int it = 0; it < 20; ++it) {
            float s = x0 + x1;
#pragma unroll
            for (int off = 1; off < 64; off <<= 1) s += __shfl_xor(s, off);
            if (s == 0.0f) break;            // exact fixed point
            x0 = clip01(3.0f * x0 - 0.9f * s);
            x1 = clip01(3.0f * x1 - 0.9f * s);
        }
        xrow[tid]      = x0;
        xrow[tid + 64] = x1;
    }
    __syncthreads();

    // ---- Phase D: elementwise LIF on rates * V (8 elems/thread) ----
    // e>>6 is uniform across each 64-lane wave segment, so the r==0 branch
    // is non-divergent and skips the V fetch entirely for silent groups.
    const float* Vrow = V + (size_t)bh * ROW2;
    float vals[8];
#pragma unroll
    for (int i = 0; i < 8; ++i) {
        const int e = tid + i * 1024;
        const float r = xrow[e >> 6];
        vals[i] = (r == 0.0f) ? 0.0f : lif_rate(r * Vrow[e]);
    }
    // (no barrier needed: phase D touches no LDS; phase E's partial[] write
    //  is followed by its own __syncthreads before any cross-thread read)

    // ---- Phase E: WTA-8192 block-wide (registers, 16 waves) ----
    for (int it = 0; it < 20; ++it) {
        float s = vals[0] + vals[1] + vals[2] + vals[3]
                + vals[4] + vals[5] + vals[6] + vals[7];
#pragma unroll
        for (int off = 1; off < 64; off <<= 1) s += __shfl_xor(s, off);
        if ((tid & 63) == 0) partial[tid >> 6] = s;
        __syncthreads();
        float S = 0.0f;
#pragma unroll
        for (int i = 0; i < 16; ++i) S += partial[i];
        if (S == 0.0f) break;                // uniform across block: exact FP
        const float c = 0.9f * S;
#pragma unroll
        for (int i = 0; i < 8; ++i)
            vals[i] = clip01(3.0f * vals[i] - c);
        __syncthreads();
    }

    float* orow = out + (size_t)bh * ROW2;
#pragma unroll
    for (int i = 0; i < 8; ++i) orow[tid + i * 1024] = vals[i];
}

extern "C" void kernel_launch(void* const* d_in, const int* in_sizes, int n_in,
                              void* d_out, int out_size, void* d_ws, size_t ws_size,
                              hipStream_t stream) {
    const float* Q = (const float*)d_in[0];
    const float* K = (const float*)d_in[1];
    const float* V = (const float*)d_in[2];
    float* out = (float*)d_out;
    k_fused<<<NBH, 1024, 0, stream>>>(Q, K, V, out);
}